// Round 1
// baseline (7824.796 us; speedup 1.0000x reference)
//
#include <hip/hip_runtime.h>
#include <hip/hip_bf16.h>

// ---------------------------------------------------------------------------
// BiLSTM-CRF on MI355X.  Pipeline:
//  k0: convert w_ih/fc_w -> bf16, bias sums
//  k1: embedding gather -> bf16 [t*64+b][512]
//  k2: input projection GEMM (bf16 MFMA 16x16x32), xp[d][t*64+b][2048] (+bias)
//  k3: persistent bidirectional LSTM recurrence, W_hh in VGPRs, flag sync
//  k4: emissions GEMM -> em[t*64+b][48] fp32
//  k5: CRF numerator per batch
//  k6: CRF forward (logsumexp as exp-matvec) per batch
//  k7: final scalar reduce
// Workspace need: ~357 MB.
// ---------------------------------------------------------------------------

typedef short short8  __attribute__((ext_vector_type(8)));
typedef short short4v __attribute__((ext_vector_type(4)));
typedef float floatx4 __attribute__((ext_vector_type(4)));

#define OFF_XP    0ULL               // [2][32768][2048] bf16  268,435,456 B
#define OFF_H     268435456ULL       // [2][32768][512]  bf16   67,108,864 B
#define OFF_EMB   335544320ULL       // [32768][512]     bf16   33,554,432 B
#define OFF_WIH   369098752ULL       // [2][2048][512]   bf16    4,194,304 B
#define OFF_FCW   373293056ULL       // [48][1024]       bf16       98,304 B
#define OFF_BIAS  373391360ULL       // [2][2048]        f32        16,384 B
#define OFF_FLAGS 373407744ULL       // [2][512][64]     int       262,144 B
#define OFF_NUM   373669888ULL       // [64] f32
#define OFF_LOGZ  373670144ULL       // [64] f32
#define OFF_EM    373670400ULL       // [32768][48] f32      6,291,456 B
#define WS_NEED   379961856ULL

__device__ __forceinline__ unsigned short f2bf(float f) {
  __hip_bfloat16 h = __float2bfloat16(f);
  unsigned short u; __builtin_memcpy(&u, &h, 2); return u;
}
__device__ __forceinline__ float bf2f(unsigned short u) {
  __hip_bfloat16 h; __builtin_memcpy(&h, &u, 2); return __bfloat162float(h);
}
__device__ __forceinline__ float sigm(float x) { return 1.0f / (1.0f + __expf(-x)); }
__device__ __forceinline__ float tanh_f(float x) {
  x = fmaxf(fminf(x, 15.0f), -15.0f);
  float e = __expf(2.0f * x);
  return (e - 1.0f) / (e + 1.0f);
}

// ---------------- k0: weight conversions ----------------
__global__ void k0_conv(const float* __restrict__ wf, const float* __restrict__ wb,
                        const float* __restrict__ fcw,
                        const float* __restrict__ bihf, const float* __restrict__ bhhf,
                        const float* __restrict__ bihb, const float* __restrict__ bhhb,
                        unsigned short* __restrict__ wih_bf,
                        unsigned short* __restrict__ fcw_bf,
                        float* __restrict__ bias) {
  int i = blockIdx.x * 256 + threadIdx.x;
  if (i < 1048576) { wih_bf[i] = f2bf(wf[i]); return; }
  int j = i - 1048576;
  if (j < 1048576) { wih_bf[1048576 + j] = f2bf(wb[j]); return; }
  j -= 1048576;
  if (j < 49152) { fcw_bf[j] = f2bf(fcw[j]); return; }
  j -= 49152;
  if (j < 2048) { bias[j] = bihf[j] + bhhf[j]; return; }
  j -= 2048;
  if (j < 2048) { bias[2048 + j] = bihb[j] + bhhb[j]; return; }
}

// ---------------- k1: embedding gather -> bf16 ----------------
__global__ void k1_embed(const float* __restrict__ tab, const int* __restrict__ x,
                         unsigned short* __restrict__ emb_bf) {
  int tid = threadIdx.x;
#pragma unroll
  for (int r = 0; r < 4; ++r) {
    int m = blockIdx.x * 4 + r;          // m = t*64 + b
    int b = m & 63, t = m >> 6;
    int tok = x[b * 512 + t];
    const float2* src = (const float2*)(tab + (size_t)tok * 512);
    float2 v = src[tid];
    unsigned int pk = (unsigned int)f2bf(v.x) | ((unsigned int)f2bf(v.y) << 16);
    ((unsigned int*)(emb_bf + (size_t)m * 512))[tid] = pk;
  }
}

// ---------------- k2: input-projection GEMM ----------------
__global__ __launch_bounds__(256) void k2_xproj(
    const unsigned short* __restrict__ emb_bf, const unsigned short* __restrict__ wih_bf,
    const float* __restrict__ bias, unsigned short* __restrict__ xp) {
  const int mt = blockIdx.x * 128;
  const int nt = blockIdx.y * 128;
  const int d  = blockIdx.z;
  const unsigned short* W = wih_bf + (size_t)d * 2048 * 512;
  __shared__ short Bs[32768];                     // 64 KB: 128n x 256k chunk
  const int tid = threadIdx.x, l = tid & 63, wv = tid >> 6;
  const int mh = wv & 1, nh = wv >> 1;
  floatx4 acc[4][4];
#pragma unroll
  for (int a = 0; a < 4; ++a)
#pragma unroll
    for (int b = 0; b < 4; ++b) acc[a][b] = (floatx4){0.f, 0.f, 0.f, 0.f};
  const unsigned short* Abase = emb_bf + (size_t)(mt + mh * 64) * 512;

  for (int kc = 0; kc < 2; ++kc) {
    __syncthreads();
#pragma unroll
    for (int i = 0; i < 16; ++i) {                // stage 64 fragments
      int f = i * 4 + wv;
      int nb2 = f & 7, ks = f >> 3;
      int n = nt + nb2 * 16 + (l & 15);
      int k = kc * 256 + ks * 32 + (l >> 4) * 8;
      short8 v = *(const short8*)(W + (size_t)n * 512 + k);
      *(short8*)(Bs + (f * 64 + l) * 8) = v;
    }
    __syncthreads();
#pragma unroll
    for (int ks = 0; ks < 8; ++ks) {
      int k0 = kc * 256 + ks * 32 + (l >> 4) * 8;
      short8 a[4];
#pragma unroll
      for (int mf = 0; mf < 4; ++mf)
        a[mf] = *(const short8*)(Abase + (size_t)(mf * 16 + (l & 15)) * 512 + k0);
#pragma unroll
      for (int nf = 0; nf < 4; ++nf) {
        short8 bfr = *(const short8*)(Bs + ((ks * 8 + nh * 4 + nf) * 64 + l) * 8);
#pragma unroll
        for (int mf = 0; mf < 4; ++mf)
          acc[mf][nf] = __builtin_amdgcn_mfma_f32_16x16x32_bf16(a[mf], bfr, acc[mf][nf], 0, 0, 0);
      }
    }
  }
  unsigned short* out = xp + (size_t)d * 32768 * 2048;
#pragma unroll
  for (int nf = 0; nf < 4; ++nf) {
    int n = nt + nh * 64 + nf * 16 + (l & 15);
    float bs = bias[d * 2048 + n];
#pragma unroll
    for (int mf = 0; mf < 4; ++mf)
#pragma unroll
      for (int r = 0; r < 4; ++r) {
        int m = mt + mh * 64 + mf * 16 + (l >> 4) * 4 + r;
        out[(size_t)m * 2048 + n] = f2bf(acc[mf][nf][r] + bs);
      }
  }
}

// ---------------- k3: persistent bidirectional LSTM ----------------
__global__ __launch_bounds__(256, 1) void k3_lstm(
    const float* __restrict__ whh_f, const float* __restrict__ whh_b,
    const unsigned short* __restrict__ xp, unsigned short* __restrict__ Hall,
    int* __restrict__ flags) {
  const int wgid = blockIdx.x;
  const int d = wgid >> 6;
  const int g = wgid & 63;
  const int tid = threadIdx.x;
  const int l = tid & 63;
  const int wv = tid >> 6;
  const float* whh = d ? whh_b : whh_f;

  // W_hh tile (32 gate-cols = cells [g*8,g*8+8) x 4 gates) as B-fragments in VGPRs.
  short8 Bf[32];
#pragma unroll
  for (int ks = 0; ks < 16; ++ks) {
#pragma unroll
    for (int nf = 0; nf < 2; ++nf) {
      int nl = nf * 16 + (l & 15);
      int gate = nl >> 3, cell = nl & 7;
      int row = gate * 512 + g * 8 + cell;
      int k0 = ks * 32 + (l >> 4) * 8;
      const float* src = whh + (size_t)row * 512 + k0;
      short8 v;
#pragma unroll
      for (int j = 0; j < 8; ++j) v[j] = (short)f2bf(src[j]);
      Bf[ks * 2 + nf] = v;
    }
  }

  __shared__ float gsh[64][36];
  const int cell_e = tid & 7;
  const int brow = tid >> 3;                    // 0..31
  float cst[2] = {0.f, 0.f};

  const size_t dbaseH = (size_t)d * 16777216;   // elems
  const size_t dbaseX = (size_t)d * 67108864;   // elems
  int* flg_d = flags + d * 512 * 64;

  for (int s = 0; s < 512; ++s) {
    const int t = d ? (511 - s) : s;

    float xpv[8];                                // prefetch (flag-independent)
#pragma unroll
    for (int q = 0; q < 2; ++q) {
      int b = brow + 32 * q;
      const unsigned short* xrow = xp + dbaseX + (size_t)(t * 64 + b) * 2048 + g * 8 + cell_e;
#pragma unroll
      for (int gate = 0; gate < 4; ++gate) xpv[q * 4 + gate] = bf2f(xrow[gate * 512]);
    }

    floatx4 acc0 = (floatx4){0.f, 0.f, 0.f, 0.f};
    floatx4 acc1 = (floatx4){0.f, 0.f, 0.f, 0.f};
    if (s > 0) {
      const int* fl = flg_d + (s - 1) * 64;
      int ok;
      do {
        int v = __hip_atomic_load(fl + l, __ATOMIC_RELAXED, __HIP_MEMORY_SCOPE_AGENT);
        ok = (v == 1);
      } while (!__all(ok));
      __builtin_amdgcn_fence(__ATOMIC_ACQUIRE, "agent");
      const int tp = d ? (t + 1) : (t - 1);
      const unsigned short* Hrow =
          Hall + dbaseH + (size_t)(tp * 64 + wv * 16 + (l & 15)) * 512 + (l >> 4) * 8;
#pragma unroll
      for (int ks = 0; ks < 16; ++ks) {
        short8 a = *(const short8*)(Hrow + ks * 32);
        acc0 = __builtin_amdgcn_mfma_f32_16x16x32_bf16(a, Bf[ks * 2 + 0], acc0, 0, 0, 0);
        acc1 = __builtin_amdgcn_mfma_f32_16x16x32_bf16(a, Bf[ks * 2 + 1], acc1, 0, 0, 0);
      }
    }
#pragma unroll
    for (int r = 0; r < 4; ++r) {
      int m = wv * 16 + (l >> 4) * 4 + r;
      gsh[m][l & 15] = acc0[r];
      gsh[m][16 + (l & 15)] = acc1[r];
    }
    __syncthreads();
#pragma unroll
    for (int q = 0; q < 2; ++q) {
      int b = brow + 32 * q;
      float gi = gsh[b][0 * 8 + cell_e] + xpv[q * 4 + 0];
      float gf = gsh[b][1 * 8 + cell_e] + xpv[q * 4 + 1];
      float gg = gsh[b][2 * 8 + cell_e] + xpv[q * 4 + 2];
      float go = gsh[b][3 * 8 + cell_e] + xpv[q * 4 + 3];
      float c = sigm(gf) * cst[q] + sigm(gi) * tanh_f(gg);
      cst[q] = c;
      float h = sigm(go) * tanh_f(c);
      Hall[dbaseH + (size_t)(t * 64 + b) * 512 + g * 8 + cell_e] = f2bf(h);
    }
    __syncthreads();   // barrier drains vmcnt: all h-stores of this wg complete
    if (tid == 0)
      __hip_atomic_store(flg_d + s * 64 + g, 1, __ATOMIC_RELEASE, __HIP_MEMORY_SCOPE_AGENT);
  }
}

// ---------------- k4: emissions GEMM ----------------
__global__ __launch_bounds__(256) void k4_emis(
    const unsigned short* __restrict__ Hall, const unsigned short* __restrict__ fcw_bf,
    const float* __restrict__ fcb, float* __restrict__ em) {
  __shared__ short Fs[48 * 520];                 // 49,920 B
  const int tid = threadIdx.x, l = tid & 63, wv = tid >> 6;
  const int Mtile = blockIdx.x * 64;
  floatx4 acc[3];
  acc[0] = acc[1] = acc[2] = (floatx4){0.f, 0.f, 0.f, 0.f};
  for (int half = 0; half < 2; ++half) {
    __syncthreads();
#pragma unroll
    for (int i = 0; i < 24; ++i) {               // 6144 short4 copies
      int e4 = (tid + i * 256) * 4;
      int n = e4 >> 9, k = e4 & 511;
      *(short4v*)(Fs + n * 520 + k) =
          *(const short4v*)(fcw_bf + (size_t)n * 1024 + half * 512 + k);
    }
    __syncthreads();
    const unsigned short* Hsrc = Hall + (size_t)half * 16777216 +
                                 (size_t)(Mtile + wv * 16 + (l & 15)) * 512 + (l >> 4) * 8;
#pragma unroll
    for (int ks = 0; ks < 16; ++ks) {
      short8 a = *(const short8*)(Hsrc + ks * 32);
#pragma unroll
      for (int nf = 0; nf < 3; ++nf) {
        short8 bfr = *(const short8*)(Fs + (nf * 16 + (l & 15)) * 520 + ks * 32 + (l >> 4) * 8);
        acc[nf] = __builtin_amdgcn_mfma_f32_16x16x32_bf16(a, bfr, acc[nf], 0, 0, 0);
      }
    }
  }
#pragma unroll
  for (int nf = 0; nf < 3; ++nf) {
    int n = nf * 16 + (l & 15);
    float bv = fcb[n];
#pragma unroll
    for (int r = 0; r < 4; ++r) {
      int m = Mtile + wv * 16 + (l >> 4) * 4 + r;
      em[(size_t)m * 48 + n] = acc[nf][r] + bv;
    }
  }
}

// ---------------- k5: CRF numerator ----------------
__global__ void k5_num(const float* __restrict__ em, const int* __restrict__ tags,
                       const float* __restrict__ start, const float* __restrict__ endt,
                       const float* __restrict__ trans, float* __restrict__ num) {
  const int b = blockIdx.x, tid = threadIdx.x;
  float s = 0.f;
  for (int t = 1 + tid; t < 512; t += 256) {
    int tg = tags[b * 512 + t], tp = tags[b * 512 + t - 1];
    s += em[(size_t)(t * 64 + b) * 48 + tg] + trans[tp * 48 + tg];
  }
  if (tid == 0) {
    int t0 = tags[b * 512];
    s += start[t0] + em[(size_t)b * 48 + t0] + endt[tags[b * 512 + 511]];
  }
  __shared__ float red[256];
  red[tid] = s;
  __syncthreads();
  for (int o = 128; o > 0; o >>= 1) {
    if (tid < o) red[tid] += red[tid + o];
    __syncthreads();
  }
  if (tid == 0) num[b] = red[0];
}

// ---------------- k6: CRF forward recursion ----------------
__global__ void k6_crf(const float* __restrict__ em, const float* __restrict__ trans,
                       const float* __restrict__ start, const float* __restrict__ endt,
                       float* __restrict__ logz) {
  const int b = blockIdx.x;
  const int j = threadIdx.x;   // 64 threads, lanes 48..63 inactive
  const bool act = j < 48;
  float Ecol[48];
#pragma unroll
  for (int i = 0; i < 48; ++i) Ecol[i] = act ? __expf(trans[i * 48 + j]) : 0.f;
  __shared__ float p[48];
  float alpha = act ? (start[j] + em[(size_t)b * 48 + j]) : -1e30f;
  for (int t = 1; t < 512; ++t) {
    float e_t = act ? em[(size_t)(t * 64 + b) * 48 + j] : 0.f;
    float m = alpha;
#pragma unroll
    for (int off = 32; off > 0; off >>= 1) m = fmaxf(m, __shfl_xor(m, off));
    float pj = act ? __expf(alpha - m) : 0.f;
    if (act) p[j] = pj;
    __syncthreads();
    float ssum = 0.f;
#pragma unroll
    for (int i = 0; i < 48; ++i) ssum += p[i] * Ecol[i];
    __syncthreads();
    alpha = act ? (m + __logf(ssum) + e_t) : -1e30f;
  }
  float v = act ? (alpha + endt[j]) : -1e30f;
  float m2 = v;
#pragma unroll
  for (int off = 32; off > 0; off >>= 1) m2 = fmaxf(m2, __shfl_xor(m2, off));
  float sz = act ? __expf(v - m2) : 0.f;
#pragma unroll
  for (int off = 32; off > 0; off >>= 1) sz += __shfl_xor(sz, off);
  if (j == 0) logz[b] = m2 + __logf(sz);
}

// ---------------- k7: final scalar ----------------
__global__ void k7_final(const float* __restrict__ num, const float* __restrict__ logz,
                         float* __restrict__ out) {
  int l = threadIdx.x;
  float v = num[l] - logz[l];
#pragma unroll
  for (int off = 32; off > 0; off >>= 1) v += __shfl_xor(v, off);
  if (l == 0) out[0] = -v * (1.0f / 64.0f);
}

// ---------------------------------------------------------------------------
extern "C" void kernel_launch(void* const* d_in, const int* in_sizes, int n_in,
                              void* d_out, int out_size, void* d_ws, size_t ws_size,
                              hipStream_t stream) {
  (void)in_sizes; (void)n_in; (void)out_size;
  if (ws_size < WS_NEED) return;   // workspace too small: fail cleanly, restructure next round

  const float* embedding = (const float*)d_in[0];
  const float* w_ih_f = (const float*)d_in[1];
  const float* w_hh_f = (const float*)d_in[2];
  const float* b_ih_f = (const float*)d_in[3];
  const float* b_hh_f = (const float*)d_in[4];
  const float* w_ih_b = (const float*)d_in[5];
  const float* w_hh_b = (const float*)d_in[6];
  const float* b_ih_b = (const float*)d_in[7];
  const float* b_hh_b = (const float*)d_in[8];
  const float* fc_w = (const float*)d_in[9];
  const float* fc_b = (const float*)d_in[10];
  const float* start_trans = (const float*)d_in[11];
  const float* end_trans = (const float*)d_in[12];
  const float* trans = (const float*)d_in[13];
  const int* x = (const int*)d_in[14];
  const int* tags = (const int*)d_in[15];

  char* ws = (char*)d_ws;
  unsigned short* xp     = (unsigned short*)(ws + OFF_XP);
  unsigned short* Hall   = (unsigned short*)(ws + OFF_H);
  unsigned short* emb_bf = (unsigned short*)(ws + OFF_EMB);
  unsigned short* wih_bf = (unsigned short*)(ws + OFF_WIH);
  unsigned short* fcw_bf = (unsigned short*)(ws + OFF_FCW);
  float* bias  = (float*)(ws + OFF_BIAS);
  int*   flags = (int*)(ws + OFF_FLAGS);
  float* num   = (float*)(ws + OFF_NUM);
  float* logz  = (float*)(ws + OFF_LOGZ);
  float* em    = (float*)(ws + OFF_EM);

  // flags need no init: ws is poisoned 0xAA (!= 1); write-once protocol.
  k0_conv<<<8400, 256, 0, stream>>>(w_ih_f, w_ih_b, fc_w, b_ih_f, b_hh_f, b_ih_b, b_hh_b,
                                    wih_bf, fcw_bf, bias);
  k1_embed<<<8192, 256, 0, stream>>>(embedding, x, emb_bf);
  k2_xproj<<<dim3(256, 16, 2), 256, 0, stream>>>(emb_bf, wih_bf, bias, xp);
  k3_lstm<<<128, 256, 0, stream>>>(w_hh_f, w_hh_b, xp, Hall, flags);
  k4_emis<<<512, 256, 0, stream>>>(Hall, fcw_bf, fc_b, em);
  k5_num<<<64, 256, 0, stream>>>(em, tags, start_trans, end_trans, trans, num);
  k6_crf<<<64, 64, 0, stream>>>(em, trans, start_trans, end_trans, logz);
  k7_final<<<1, 64, 0, stream>>>(num, logz, (float*)d_out);
}

// Round 2
// 4321.767 us; speedup vs baseline: 1.8106x; 1.8106x over previous
//
#include <hip/hip_runtime.h>
#include <hip/hip_bf16.h>

// ---------------------------------------------------------------------------
// BiLSTM-CRF on MI355X, round 2.
//  k0: weight conversions + bias sums + zero sync counters
//  k1: embedding gather -> bf16 [t*64+b][512]
//  k2: input projection GEMM -> xq in per-(d,g,t) 4KB blocks (LDS transpose epilogue)
//  k3: persistent BiLSTM; W_hh in VGPRs; FENCE-FREE counter sync:
//      H stores = agent atomic 4B (write-through, L2 clean), __syncthreads drains
//      vmcnt, relaxed atomicAdd on padded counter; consumers poll + cached loads.
//  k4: emissions GEMM -> em[t*64+b][48] fp32
//  k5/k6/k7: CRF numerator / forward / final scalar
// ---------------------------------------------------------------------------

typedef short short8  __attribute__((ext_vector_type(8)));
typedef short short4v __attribute__((ext_vector_type(4)));
typedef float floatx4 __attribute__((ext_vector_type(4)));

#define OFF_XQ    0ULL               // [2*64][512] blocks of 2048 bf16  268,435,456 B
#define OFF_H     268435456ULL       // [2][512][64][512] bf16 (perm'd t) 67,108,864 B
#define OFF_EMB   335544320ULL       // [32768][512] bf16                 33,554,432 B
#define OFF_WIH   369098752ULL       // [2][2048][512] bf16                4,194,304 B
#define OFF_FCW   373293056ULL       // [48][1024] bf16                       98,304 B
#define OFF_BIAS  373391360ULL       // [2][2048] f32                         16,384 B
#define OFF_CNT   373407744ULL       // [2][512][32] u32 (128B padded)       131,072 B
#define OFF_EM    373538816ULL       // [32768][48] f32                    6,291,456 B
#define OFF_NUM   379830272ULL       // [64] f32
#define OFF_LOGZ  379830528ULL       // [64] f32
#define WS_NEED   379830784ULL       // < 379,961,856 proven available in round 1

__device__ __forceinline__ unsigned short f2bf(float f) {
  __hip_bfloat16 h = __float2bfloat16(f);
  unsigned short u; __builtin_memcpy(&u, &h, 2); return u;
}
__device__ __forceinline__ float bf2f(unsigned short u) {
  __hip_bfloat16 h; __builtin_memcpy(&h, &u, 2); return __bfloat162float(h);
}
__device__ __forceinline__ float sigm(float x) { return 1.0f / (1.0f + __expf(-x)); }
__device__ __forceinline__ float tanh_f(float x) {
  x = fmaxf(fminf(x, 15.0f), -15.0f);
  float e = __expf(2.0f * x);
  return (e - 1.0f) / (e + 1.0f);
}
// bijective time->block scramble (defeats sequential-line prefetch of unwritten blocks)
__device__ __forceinline__ int permt(int t) { return (t * 167) & 511; }

// ---------------- k0: conversions + counter init ----------------
__global__ void k0_conv(const float* __restrict__ wf, const float* __restrict__ wb,
                        const float* __restrict__ fcw,
                        const float* __restrict__ bihf, const float* __restrict__ bhhf,
                        const float* __restrict__ bihb, const float* __restrict__ bhhb,
                        unsigned short* __restrict__ wih_bf,
                        unsigned short* __restrict__ fcw_bf,
                        float* __restrict__ bias,
                        unsigned int* __restrict__ cnt) {
  int i = blockIdx.x * 256 + threadIdx.x;
  if (i < 1048576) { wih_bf[i] = f2bf(wf[i]); return; }
  int j = i - 1048576;
  if (j < 1048576) { wih_bf[1048576 + j] = f2bf(wb[j]); return; }
  j -= 1048576;
  if (j < 49152) { fcw_bf[j] = f2bf(fcw[j]); return; }
  j -= 49152;
  if (j < 2048) { bias[j] = bihf[j] + bhhf[j]; return; }
  j -= 2048;
  if (j < 2048) { bias[2048 + j] = bihb[j] + bhhb[j]; return; }
  j -= 2048;
  if (j < 32768) { cnt[j] = 0u; return; }
}

// ---------------- k1: embedding gather -> bf16 ----------------
__global__ void k1_embed(const float* __restrict__ tab, const int* __restrict__ x,
                         unsigned short* __restrict__ emb_bf) {
  int tid = threadIdx.x;
#pragma unroll
  for (int r = 0; r < 4; ++r) {
    int m = blockIdx.x * 4 + r;          // m = t*64 + b
    int b = m & 63, t = m >> 6;
    int tok = x[b * 512 + t];
    const float2* src = (const float2*)(tab + (size_t)tok * 512);
    float2 v = src[tid];
    unsigned int pk = (unsigned int)f2bf(v.x) | ((unsigned int)f2bf(v.y) << 16);
    ((unsigned int*)(emb_bf + (size_t)m * 512))[tid] = pk;
  }
}

// ---------------- k2: input-projection GEMM -> xq layout ----------------
// xq block index (d*64+g)*512 + t, 2048 bf16 per block, inner: gate*512 + b*8 + ce
__global__ __launch_bounds__(256) void k2_xproj(
    const unsigned short* __restrict__ emb_bf, const unsigned short* __restrict__ wih_bf,
    const float* __restrict__ bias, unsigned short* __restrict__ xq) {
  const int mt = blockIdx.x * 128;
  const int nt = blockIdx.y * 128;
  const int d  = blockIdx.z;
  const unsigned short* W = wih_bf + (size_t)d * 2048 * 512;
  __shared__ short Bs[32768];                     // 64 KB (also epilogue scratch)
  const int tid = threadIdx.x, l = tid & 63, wv = tid >> 6;
  const int mh = wv & 1, nh = wv >> 1;
  floatx4 acc[4][4];
#pragma unroll
  for (int a = 0; a < 4; ++a)
#pragma unroll
    for (int b = 0; b < 4; ++b) acc[a][b] = (floatx4){0.f, 0.f, 0.f, 0.f};
  const unsigned short* Abase = emb_bf + (size_t)(mt + mh * 64) * 512;

  for (int kc = 0; kc < 2; ++kc) {
    __syncthreads();
#pragma unroll
    for (int i = 0; i < 16; ++i) {                // stage 64 B-fragments
      int f = i * 4 + wv;
      int nb2 = f & 7, ks = f >> 3;
      int n = nt + nb2 * 16 + (l & 15);
      int k = kc * 256 + ks * 32 + (l >> 4) * 8;
      short8 v = *(const short8*)(W + (size_t)n * 512 + k);
      *(short8*)(Bs + (f * 64 + l) * 8) = v;
    }
    __syncthreads();
#pragma unroll
    for (int ks = 0; ks < 8; ++ks) {
      int k0 = kc * 256 + ks * 32 + (l >> 4) * 8;
      short8 a[4];
#pragma unroll
      for (int mf = 0; mf < 4; ++mf)
        a[mf] = *(const short8*)(Abase + (size_t)(mf * 16 + (l & 15)) * 512 + k0);
#pragma unroll
      for (int nf = 0; nf < 4; ++nf) {
        short8 bfr = *(const short8*)(Bs + ((ks * 8 + nh * 4 + nf) * 64 + l) * 8);
#pragma unroll
        for (int mf = 0; mf < 4; ++mf)
          acc[mf][nf] = __builtin_amdgcn_mfma_f32_16x16x32_bf16(a[mf], bfr, acc[mf][nf], 0, 0, 0);
      }
    }
  }
  // ---- epilogue: LDS transpose into xq block layout ----
  __syncthreads();
#pragma unroll
  for (int nf = 0; nf < 4; ++nf) {
    int nl = nh * 64 + nf * 16 + (l & 15);
    float bs = bias[d * 2048 + nt + nl];
#pragma unroll
    for (int mf = 0; mf < 4; ++mf)
#pragma unroll
      for (int r = 0; r < 4; ++r) {
        int ml = mh * 64 + mf * 16 + (l >> 4) * 4 + r;
        Bs[ml * 136 + nl] = (short)f2bf(acc[mf][nf][r] + bs);  // stride 136: 16B-aligned rows
      }
  }
  __syncthreads();
  const int chunk = tid >> 3, sub = tid & 7;      // 32 chunks x 8 threads
  const int g_l = chunk & 15, t_l = chunk >> 4;
  const int gate = nt >> 9, g0 = (nt & 511) >> 3;
  size_t base = (((size_t)(d * 64 + g0 + g_l) * 512) + (size_t)(blockIdx.x * 2 + t_l)) * 2048
                + (size_t)gate * 512 + (size_t)sub * 64;
#pragma unroll
  for (int i = 0; i < 8; ++i) {                   // b = sub*8+i, pos = b*8+ce
    short8 v = *(const short8*)(Bs + (t_l * 64 + sub * 8 + i) * 136 + g_l * 8);
    *(short8*)(xq + base + i * 8) = v;
  }
}

// ---------------- k3: persistent BiLSTM, fence-free sync ----------------
__global__ __launch_bounds__(256, 1) void k3_lstm(
    const float* __restrict__ whh_f, const float* __restrict__ whh_b,
    const unsigned short* __restrict__ xq, unsigned short* __restrict__ Hall,
    unsigned int* __restrict__ cnt) {
  const int wgid = blockIdx.x;
  const int d = wgid >> 6, g = wgid & 63;
  const int tid = threadIdx.x, l = tid & 63, wv = tid >> 6;
  const float* whh = d ? whh_b : whh_f;

  // W_hh tile (cells [g*8,g*8+8) x 4 gates) as 32 B-fragments in VGPRs.
  short8 Bf[32];
#pragma unroll
  for (int ks = 0; ks < 16; ++ks) {
#pragma unroll
    for (int nf = 0; nf < 2; ++nf) {
      int nl = nf * 16 + (l & 15);
      int gate = nl >> 3, cell = nl & 7;
      int row = gate * 512 + g * 8 + cell;
      int k0 = ks * 32 + (l >> 4) * 8;
      const float* src = whh + (size_t)row * 512 + k0;
      short8 v;
#pragma unroll
      for (int j = 0; j < 8; ++j) v[j] = (short)f2bf(src[j]);
      Bf[ks * 2 + nf] = v;
    }
  }

  __shared__ float gsh2[32][66];                  // [gate*8+cell][batch], transposed
  const int eb = tid & 63, pr = tid >> 6;         // elementwise: batch eb, cell pair pr
  float cst[2] = {0.f, 0.f};

  const unsigned short* Hd = Hall + (size_t)d * 16777216;
  unsigned int* Hw = (unsigned int*)Hall + (size_t)d * 8388608;
  unsigned int* cd = cnt + d * 16384;             // [512][32] u32, 128B stride
  const unsigned short* xqd = xq + ((size_t)(d * 64 + g) * 512) * 2048;

  for (int s = 0; s < 512; ++s) {
    const int t = d ? (511 - s) : s;

    // prefetch xq (single-use, issued before the wait)
    const unsigned int* xb = (const unsigned int*)(xqd + (size_t)t * 2048);
    unsigned int xg[4];
#pragma unroll
    for (int gate = 0; gate < 4; ++gate) xg[gate] = xb[gate * 256 + eb * 4 + pr];

    floatx4 acc0 = (floatx4){0.f, 0.f, 0.f, 0.f};
    floatx4 acc1 = (floatx4){0.f, 0.f, 0.f, 0.f};
    if (s > 0) {
      while (__hip_atomic_load(&cd[(s - 1) * 32], __ATOMIC_RELAXED, __HIP_MEMORY_SCOPE_AGENT) < 64u)
        __builtin_amdgcn_s_sleep(1);
      asm volatile("" ::: "memory");              // pin H loads after poll (compiler only)
      const int tp = d ? (t + 1) : (t - 1);
      const unsigned short* Hrow = Hd + (size_t)permt(tp) * 32768
                                   + (size_t)(wv * 16 + (l & 15)) * 512 + (l >> 4) * 8;
      short8 af[16];
#pragma unroll
      for (int ks = 0; ks < 16; ++ks) af[ks] = *(const short8*)(Hrow + ks * 32);
#pragma unroll
      for (int ks = 0; ks < 16; ++ks) {
        acc0 = __builtin_amdgcn_mfma_f32_16x16x32_bf16(af[ks], Bf[ks * 2 + 0], acc0, 0, 0, 0);
        acc1 = __builtin_amdgcn_mfma_f32_16x16x32_bf16(af[ks], Bf[ks * 2 + 1], acc1, 0, 0, 0);
      }
    }
    // stage gates transposed: row = gate*8+cell (0..31), col = batch
#pragma unroll
    for (int r = 0; r < 4; ++r) {
      int m = wv * 16 + (l >> 4) * 4 + r;
      gsh2[l & 15][m] = acc0[r];
      gsh2[16 + (l & 15)][m] = acc1[r];
    }
    __syncthreads();
    // elementwise: thread owns cells pr*2, pr*2+1 of batch eb
    float h2[2];
#pragma unroll
    for (int ci = 0; ci < 2; ++ci) {
      int cl = pr * 2 + ci;
      float gi = gsh2[0 + cl][eb]  + bf2f((unsigned short)(xg[0] >> (ci * 16)));
      float gf = gsh2[8 + cl][eb]  + bf2f((unsigned short)(xg[1] >> (ci * 16)));
      float gg = gsh2[16 + cl][eb] + bf2f((unsigned short)(xg[2] >> (ci * 16)));
      float go = gsh2[24 + cl][eb] + bf2f((unsigned short)(xg[3] >> (ci * 16)));
      float c = sigm(gf) * cst[ci] + sigm(gi) * tanh_f(gg);
      cst[ci] = c;
      h2[ci] = sigm(go) * tanh_f(c);
    }
    unsigned int hp = (unsigned int)f2bf(h2[0]) | ((unsigned int)f2bf(h2[1]) << 16);
    // write-through agent atomic store: L2 stays clean, lands at coherence point
    __hip_atomic_store(&Hw[(size_t)permt(t) * 16384 + eb * 256 + g * 4 + pr], hp,
                       __ATOMIC_RELAXED, __HIP_MEMORY_SCOPE_AGENT);
    __syncthreads();   // drains vmcnt(0): ALL threads' H stores complete at L3
    if (tid == 0)
      __hip_atomic_fetch_add(&cd[s * 32], 1u, __ATOMIC_RELAXED, __HIP_MEMORY_SCOPE_AGENT);
  }
}

// ---------------- k4: emissions GEMM (new H layout) ----------------
__global__ __launch_bounds__(256) void k4_emis(
    const unsigned short* __restrict__ Hall, const unsigned short* __restrict__ fcw_bf,
    const float* __restrict__ fcb, float* __restrict__ em) {
  __shared__ short Fs[48 * 520];
  const int tid = threadIdx.x, l = tid & 63, wv = tid >> 6;
  const int t = blockIdx.x;                      // M-tile 64 = one timestep
  floatx4 acc[3];
  acc[0] = acc[1] = acc[2] = (floatx4){0.f, 0.f, 0.f, 0.f};
  for (int half = 0; half < 2; ++half) {
    __syncthreads();
#pragma unroll
    for (int i = 0; i < 24; ++i) {
      int e4 = (tid + i * 256) * 4;
      int n = e4 >> 9, k = e4 & 511;
      *(short4v*)(Fs + n * 520 + k) =
          *(const short4v*)(fcw_bf + (size_t)n * 1024 + half * 512 + k);
    }
    __syncthreads();
    const unsigned short* Hsrc = Hall + (size_t)half * 16777216 + (size_t)permt(t) * 32768
                                 + (size_t)(wv * 16 + (l & 15)) * 512 + (l >> 4) * 8;
#pragma unroll
    for (int ks = 0; ks < 16; ++ks) {
      short8 a = *(const short8*)(Hsrc + ks * 32);
#pragma unroll
      for (int nf = 0; nf < 3; ++nf) {
        short8 bfr = *(const short8*)(Fs + (nf * 16 + (l & 15)) * 520 + ks * 32 + (l >> 4) * 8);
        acc[nf] = __builtin_amdgcn_mfma_f32_16x16x32_bf16(a, bfr, acc[nf], 0, 0, 0);
      }
    }
  }
#pragma unroll
  for (int nf = 0; nf < 3; ++nf) {
    int n = nf * 16 + (l & 15);
    float bv = fcb[n];
#pragma unroll
    for (int r = 0; r < 4; ++r) {
      int m = wv * 16 + (l >> 4) * 4 + r;        // batch
      em[((size_t)t * 64 + m) * 48 + n] = acc[nf][r] + bv;
    }
  }
}

// ---------------- k5: CRF numerator ----------------
__global__ void k5_num(const float* __restrict__ em, const int* __restrict__ tags,
                       const float* __restrict__ start, const float* __restrict__ endt,
                       const float* __restrict__ trans, float* __restrict__ num) {
  const int b = blockIdx.x, tid = threadIdx.x;
  float s = 0.f;
  for (int t = 1 + tid; t < 512; t += 256) {
    int tg = tags[b * 512 + t], tp = tags[b * 512 + t - 1];
    s += em[(size_t)(t * 64 + b) * 48 + tg] + trans[tp * 48 + tg];
  }
  if (tid == 0) {
    int t0 = tags[b * 512];
    s += start[t0] + em[(size_t)b * 48 + t0] + endt[tags[b * 512 + 511]];
  }
  __shared__ float red[256];
  red[tid] = s;
  __syncthreads();
  for (int o = 128; o > 0; o >>= 1) {
    if (tid < o) red[tid] += red[tid + o];
    __syncthreads();
  }
  if (tid == 0) num[b] = red[0];
}

// ---------------- k6: CRF forward recursion ----------------
__global__ void k6_crf(const float* __restrict__ em, const float* __restrict__ trans,
                       const float* __restrict__ start, const float* __restrict__ endt,
                       float* __restrict__ logz) {
  const int b = blockIdx.x;
  const int j = threadIdx.x;   // 64 threads, lanes 48..63 inactive
  const bool act = j < 48;
  float Ecol[48];
#pragma unroll
  for (int i = 0; i < 48; ++i) Ecol[i] = act ? __expf(trans[i * 48 + j]) : 0.f;
  __shared__ float p[48];
  float alpha = act ? (start[j] + em[(size_t)b * 48 + j]) : -1e30f;
  for (int t = 1; t < 512; ++t) {
    float e_t = act ? em[(size_t)(t * 64 + b) * 48 + j] : 0.f;
    float m = alpha;
#pragma unroll
    for (int off = 32; off > 0; off >>= 1) m = fmaxf(m, __shfl_xor(m, off));
    float pj = act ? __expf(alpha - m) : 0.f;
    if (act) p[j] = pj;
    __syncthreads();
    float ssum = 0.f;
#pragma unroll
    for (int i = 0; i < 48; ++i) ssum += p[i] * Ecol[i];
    __syncthreads();
    alpha = act ? (m + __logf(ssum) + e_t) : -1e30f;
  }
  float v = act ? (alpha + endt[j]) : -1e30f;
  float m2 = v;
#pragma unroll
  for (int off = 32; off > 0; off >>= 1) m2 = fmaxf(m2, __shfl_xor(m2, off));
  float sz = act ? __expf(v - m2) : 0.f;
#pragma unroll
  for (int off = 32; off > 0; off >>= 1) sz += __shfl_xor(sz, off);
  if (j == 0) logz[b] = m2 + __logf(sz);
}

// ---------------- k7: final scalar ----------------
__global__ void k7_final(const float* __restrict__ num, const float* __restrict__ logz,
                         float* __restrict__ out) {
  int l = threadIdx.x;
  float v = num[l] - logz[l];
#pragma unroll
  for (int off = 32; off > 0; off >>= 1) v += __shfl_xor(v, off);
  if (l == 0) out[0] = -v * (1.0f / 64.0f);
}

// ---------------------------------------------------------------------------
extern "C" void kernel_launch(void* const* d_in, const int* in_sizes, int n_in,
                              void* d_out, int out_size, void* d_ws, size_t ws_size,
                              hipStream_t stream) {
  (void)in_sizes; (void)n_in; (void)out_size;
  if (ws_size < WS_NEED) return;

  const float* embedding = (const float*)d_in[0];
  const float* w_ih_f = (const float*)d_in[1];
  const float* w_hh_f = (const float*)d_in[2];
  const float* b_ih_f = (const float*)d_in[3];
  const float* b_hh_f = (const float*)d_in[4];
  const float* w_ih_b = (const float*)d_in[5];
  const float* w_hh_b = (const float*)d_in[6];
  const float* b_ih_b = (const float*)d_in[7];
  const float* b_hh_b = (const float*)d_in[8];
  const float* fc_w = (const float*)d_in[9];
  const float* fc_b = (const float*)d_in[10];
  const float* start_trans = (const float*)d_in[11];
  const float* end_trans = (const float*)d_in[12];
  const float* trans = (const float*)d_in[13];
  const int* x = (const int*)d_in[14];
  const int* tags = (const int*)d_in[15];

  char* ws = (char*)d_ws;
  unsigned short* xq     = (unsigned short*)(ws + OFF_XQ);
  unsigned short* Hall   = (unsigned short*)(ws + OFF_H);
  unsigned short* emb_bf = (unsigned short*)(ws + OFF_EMB);
  unsigned short* wih_bf = (unsigned short*)(ws + OFF_WIH);
  unsigned short* fcw_bf = (unsigned short*)(ws + OFF_FCW);
  float* bias  = (float*)(ws + OFF_BIAS);
  unsigned int* cnt = (unsigned int*)(ws + OFF_CNT);
  float* em    = (float*)(ws + OFF_EM);
  float* num   = (float*)(ws + OFF_NUM);
  float* logz  = (float*)(ws + OFF_LOGZ);

  k0_conv<<<8528, 256, 0, stream>>>(w_ih_f, w_ih_b, fc_w, b_ih_f, b_hh_f, b_ih_b, b_hh_b,
                                    wih_bf, fcw_bf, bias, cnt);
  k1_embed<<<8192, 256, 0, stream>>>(embedding, x, emb_bf);
  k2_xproj<<<dim3(256, 16, 2), 256, 0, stream>>>(emb_bf, wih_bf, bias, xq);
  k3_lstm<<<128, 256, 0, stream>>>(w_hh_f, w_hh_b, xq, Hall, cnt);
  k4_emis<<<512, 256, 0, stream>>>(Hall, fcw_bf, fc_b, em);
  k5_num<<<64, 256, 0, stream>>>(em, tags, start_trans, end_trans, trans, num);
  k6_crf<<<64, 64, 0, stream>>>(em, trans, start_trans, end_trans, logz);
  k7_final<<<1, 64, 0, stream>>>(num, logz, (float*)d_out);
}

// Round 3
// 4301.326 us; speedup vs baseline: 1.8192x; 1.0048x over previous
//
#include <hip/hip_runtime.h>
#include <hip/hip_bf16.h>

// ---------------------------------------------------------------------------
// BiLSTM-CRF on MI355X, round 3.
//  k0: weight conversions + bias sums
//  k1: embedding gather -> bf16 [t*64+b][512]
//  k2: input projection GEMM -> xq in per-(d,g,t) 4KB blocks (LDS transpose epilogue)
//  k3: persistent BiLSTM; W_hh in VGPRs; fence-free write-through sync.
//      Round-3 change: single atomicAdd counter (hot-line RMW + 512-wave poll storm)
//      replaced by write-once flags x4 replicas; wave wv polls replica wv only.
//      Flags alias the em region (poisoned 0xAA pre-launch, written by k4 post-k3).
//  k4: emissions GEMM -> em[t*64+b][48] fp32
//  k5/k6/k7: CRF numerator / forward / final scalar
// ---------------------------------------------------------------------------

typedef short short8  __attribute__((ext_vector_type(8)));
typedef short short4v __attribute__((ext_vector_type(4)));
typedef float floatx4 __attribute__((ext_vector_type(4)));

#define OFF_XQ    0ULL               // [2*64][512] blocks of 2048 bf16  268,435,456 B
#define OFF_H     268435456ULL       // [2][512][64][512] bf16 (perm'd t) 67,108,864 B
#define OFF_EMB   335544320ULL       // [32768][512] bf16                 33,554,432 B
#define OFF_WIH   369098752ULL       // [2][2048][512] bf16                4,194,304 B
#define OFF_FCW   373293056ULL       // [48][1024] bf16                       98,304 B
#define OFF_BIAS  373391360ULL       // [2][2048] f32                         16,384 B
#define OFF_EM    373538816ULL       // [32768][48] f32                    6,291,456 B
                                     // (flags [2][512][4][64] u32 = 1 MB alias here)
#define OFF_NUM   379830272ULL       // [64] f32
#define OFF_LOGZ  379830528ULL       // [64] f32
#define WS_NEED   379830784ULL

__device__ __forceinline__ unsigned short f2bf(float f) {
  __hip_bfloat16 h = __float2bfloat16(f);
  unsigned short u; __builtin_memcpy(&u, &h, 2); return u;
}
__device__ __forceinline__ float bf2f(unsigned short u) {
  __hip_bfloat16 h; __builtin_memcpy(&h, &u, 2); return __bfloat162float(h);
}
__device__ __forceinline__ float sigm(float x) { return 1.0f / (1.0f + __expf(-x)); }
__device__ __forceinline__ float tanh_f(float x) {
  x = fmaxf(fminf(x, 15.0f), -15.0f);
  float e = __expf(2.0f * x);
  return (e - 1.0f) / (e + 1.0f);
}
// bijective time->block scramble (defeats sequential-line prefetch of unwritten blocks)
__device__ __forceinline__ int permt(int t) { return (t * 167) & 511; }

// ---------------- k0: conversions ----------------
__global__ void k0_conv(const float* __restrict__ wf, const float* __restrict__ wb,
                        const float* __restrict__ fcw,
                        const float* __restrict__ bihf, const float* __restrict__ bhhf,
                        const float* __restrict__ bihb, const float* __restrict__ bhhb,
                        unsigned short* __restrict__ wih_bf,
                        unsigned short* __restrict__ fcw_bf,
                        float* __restrict__ bias) {
  int i = blockIdx.x * 256 + threadIdx.x;
  if (i < 1048576) { wih_bf[i] = f2bf(wf[i]); return; }
  int j = i - 1048576;
  if (j < 1048576) { wih_bf[1048576 + j] = f2bf(wb[j]); return; }
  j -= 1048576;
  if (j < 49152) { fcw_bf[j] = f2bf(fcw[j]); return; }
  j -= 49152;
  if (j < 2048) { bias[j] = bihf[j] + bhhf[j]; return; }
  j -= 2048;
  if (j < 2048) { bias[2048 + j] = bihb[j] + bhhb[j]; return; }
}

// ---------------- k1: embedding gather -> bf16 ----------------
__global__ void k1_embed(const float* __restrict__ tab, const int* __restrict__ x,
                         unsigned short* __restrict__ emb_bf) {
  int tid = threadIdx.x;
#pragma unroll
  for (int r = 0; r < 4; ++r) {
    int m = blockIdx.x * 4 + r;          // m = t*64 + b
    int b = m & 63, t = m >> 6;
    int tok = x[b * 512 + t];
    const float2* src = (const float2*)(tab + (size_t)tok * 512);
    float2 v = src[tid];
    unsigned int pk = (unsigned int)f2bf(v.x) | ((unsigned int)f2bf(v.y) << 16);
    ((unsigned int*)(emb_bf + (size_t)m * 512))[tid] = pk;
  }
}

// ---------------- k2: input-projection GEMM -> xq layout ----------------
// xq block index (d*64+g)*512 + t, 2048 bf16 per block, inner: gate*512 + b*8 + ce
__global__ __launch_bounds__(256) void k2_xproj(
    const unsigned short* __restrict__ emb_bf, const unsigned short* __restrict__ wih_bf,
    const float* __restrict__ bias, unsigned short* __restrict__ xq) {
  const int mt = blockIdx.x * 128;
  const int nt = blockIdx.y * 128;
  const int d  = blockIdx.z;
  const unsigned short* W = wih_bf + (size_t)d * 2048 * 512;
  __shared__ short Bs[32768];                     // 64 KB (also epilogue scratch)
  const int tid = threadIdx.x, l = tid & 63, wv = tid >> 6;
  const int mh = wv & 1, nh = wv >> 1;
  floatx4 acc[4][4];
#pragma unroll
  for (int a = 0; a < 4; ++a)
#pragma unroll
    for (int b = 0; b < 4; ++b) acc[a][b] = (floatx4){0.f, 0.f, 0.f, 0.f};
  const unsigned short* Abase = emb_bf + (size_t)(mt + mh * 64) * 512;

  for (int kc = 0; kc < 2; ++kc) {
    __syncthreads();
#pragma unroll
    for (int i = 0; i < 16; ++i) {                // stage 64 B-fragments
      int f = i * 4 + wv;
      int nb2 = f & 7, ks = f >> 3;
      int n = nt + nb2 * 16 + (l & 15);
      int k = kc * 256 + ks * 32 + (l >> 4) * 8;
      short8 v = *(const short8*)(W + (size_t)n * 512 + k);
      *(short8*)(Bs + (f * 64 + l) * 8) = v;
    }
    __syncthreads();
#pragma unroll
    for (int ks = 0; ks < 8; ++ks) {
      int k0 = kc * 256 + ks * 32 + (l >> 4) * 8;
      short8 a[4];
#pragma unroll
      for (int mf = 0; mf < 4; ++mf)
        a[mf] = *(const short8*)(Abase + (size_t)(mf * 16 + (l & 15)) * 512 + k0);
#pragma unroll
      for (int nf = 0; nf < 4; ++nf) {
        short8 bfr = *(const short8*)(Bs + ((ks * 8 + nh * 4 + nf) * 64 + l) * 8);
#pragma unroll
        for (int mf = 0; mf < 4; ++mf)
          acc[mf][nf] = __builtin_amdgcn_mfma_f32_16x16x32_bf16(a[mf], bfr, acc[mf][nf], 0, 0, 0);
      }
    }
  }
  // ---- epilogue: LDS transpose into xq block layout ----
  __syncthreads();
#pragma unroll
  for (int nf = 0; nf < 4; ++nf) {
    int nl = nh * 64 + nf * 16 + (l & 15);
    float bs = bias[d * 2048 + nt + nl];
#pragma unroll
    for (int mf = 0; mf < 4; ++mf)
#pragma unroll
      for (int r = 0; r < 4; ++r) {
        int ml = mh * 64 + mf * 16 + (l >> 4) * 4 + r;
        Bs[ml * 136 + nl] = (short)f2bf(acc[mf][nf][r] + bs);  // stride 136: 16B-aligned rows
      }
  }
  __syncthreads();
  const int chunk = tid >> 3, sub = tid & 7;      // 32 chunks x 8 threads
  const int g_l = chunk & 15, t_l = chunk >> 4;
  const int gate = nt >> 9, g0 = (nt & 511) >> 3;
  size_t base = (((size_t)(d * 64 + g0 + g_l) * 512) + (size_t)(blockIdx.x * 2 + t_l)) * 2048
                + (size_t)gate * 512 + (size_t)sub * 64;
#pragma unroll
  for (int i = 0; i < 8; ++i) {                   // b = sub*8+i, pos = b*8+ce
    short8 v = *(const short8*)(Bs + (t_l * 64 + sub * 8 + i) * 136 + g_l * 8);
    *(short8*)(xq + base + i * 8) = v;
  }
}

// ---------------- k3: persistent BiLSTM, fence-free flag sync ----------------
__global__ __launch_bounds__(256, 1) void k3_lstm(
    const float* __restrict__ whh_f, const float* __restrict__ whh_b,
    const unsigned short* __restrict__ xq, unsigned short* __restrict__ Hall,
    unsigned int* __restrict__ flags) {
  const int wgid = blockIdx.x;
  const int d = wgid >> 6, g = wgid & 63;
  const int tid = threadIdx.x, l = tid & 63, wv = tid >> 6;
  const float* whh = d ? whh_b : whh_f;

  // W_hh tile (cells [g*8,g*8+8) x 4 gates) as 32 B-fragments in VGPRs.
  short8 Bf[32];
#pragma unroll
  for (int ks = 0; ks < 16; ++ks) {
#pragma unroll
    for (int nf = 0; nf < 2; ++nf) {
      int nl = nf * 16 + (l & 15);
      int gate = nl >> 3, cell = nl & 7;
      int row = gate * 512 + g * 8 + cell;
      int k0 = ks * 32 + (l >> 4) * 8;
      const float* src = whh + (size_t)row * 512 + k0;
      short8 v;
#pragma unroll
      for (int j = 0; j < 8; ++j) v[j] = (short)f2bf(src[j]);
      Bf[ks * 2 + nf] = v;
    }
  }

  __shared__ float gsh2[32][66];                  // [gate*8+cell][batch], transposed
  const int eb = tid & 63, pr = tid >> 6;         // elementwise: batch eb, cell pair pr
  float cst[2] = {0.f, 0.f};

  const unsigned short* Hd = Hall + (size_t)d * 16777216;
  unsigned int* Hw = (unsigned int*)Hall + (size_t)d * 8388608;
  const unsigned short* xqd = xq + ((size_t)(d * 64 + g) * 512) * 2048;
  unsigned int* flg_d = flags + (size_t)d * 512 * 256;   // [512][4 replicas][64]

  for (int s = 0; s < 512; ++s) {
    const int t = d ? (511 - s) : s;

    // prefetch xq (single-use, issued before the wait)
    const unsigned int* xb = (const unsigned int*)(xqd + (size_t)t * 2048);
    unsigned int xg[4];
#pragma unroll
    for (int gate = 0; gate < 4; ++gate) xg[gate] = xb[gate * 256 + eb * 4 + pr];

    floatx4 acc0 = (floatx4){0.f, 0.f, 0.f, 0.f};
    floatx4 acc1 = (floatx4){0.f, 0.f, 0.f, 0.f};
    if (s > 0) {
      // wave wv polls replica wv: one 64-lane vector atomic load (4 lines), no RMW
      const unsigned int* fp = flg_d + (size_t)(s - 1) * 256 + wv * 64 + l;
      for (;;) {
        unsigned int v = __hip_atomic_load(fp, __ATOMIC_RELAXED, __HIP_MEMORY_SCOPE_AGENT);
        if (__all(v == 1u)) break;
        __builtin_amdgcn_s_sleep(1);
      }
      asm volatile("" ::: "memory");              // pin H loads after poll (compiler only)
      const int tp = d ? (t + 1) : (t - 1);
      const unsigned short* Hrow = Hd + (size_t)permt(tp) * 32768
                                   + (size_t)(wv * 16 + (l & 15)) * 512 + (l >> 4) * 8;
      short8 af[16];
#pragma unroll
      for (int ks = 0; ks < 16; ++ks) af[ks] = *(const short8*)(Hrow + ks * 32);
#pragma unroll
      for (int ks = 0; ks < 16; ++ks) {
        acc0 = __builtin_amdgcn_mfma_f32_16x16x32_bf16(af[ks], Bf[ks * 2 + 0], acc0, 0, 0, 0);
        acc1 = __builtin_amdgcn_mfma_f32_16x16x32_bf16(af[ks], Bf[ks * 2 + 1], acc1, 0, 0, 0);
      }
    }
    // stage gates transposed: row = gate*8+cell (0..31), col = batch
#pragma unroll
    for (int r = 0; r < 4; ++r) {
      int m = wv * 16 + (l >> 4) * 4 + r;
      gsh2[l & 15][m] = acc0[r];
      gsh2[16 + (l & 15)][m] = acc1[r];
    }
    __syncthreads();
    // elementwise: thread owns cells pr*2, pr*2+1 of batch eb
    float h2[2];
#pragma unroll
    for (int ci = 0; ci < 2; ++ci) {
      int cl = pr * 2 + ci;
      float gi = gsh2[0 + cl][eb]  + bf2f((unsigned short)(xg[0] >> (ci * 16)));
      float gf = gsh2[8 + cl][eb]  + bf2f((unsigned short)(xg[1] >> (ci * 16)));
      float gg = gsh2[16 + cl][eb] + bf2f((unsigned short)(xg[2] >> (ci * 16)));
      float go = gsh2[24 + cl][eb] + bf2f((unsigned short)(xg[3] >> (ci * 16)));
      float c = sigm(gf) * cst[ci] + sigm(gi) * tanh_f(gg);
      cst[ci] = c;
      h2[ci] = sigm(go) * tanh_f(c);
    }
    unsigned int hp = (unsigned int)f2bf(h2[0]) | ((unsigned int)f2bf(h2[1]) << 16);
    // write-through agent atomic store: L2 stays clean, lands at coherence point
    __hip_atomic_store(&Hw[(size_t)permt(t) * 16384 + eb * 256 + g * 4 + pr], hp,
                       __ATOMIC_RELAXED, __HIP_MEMORY_SCOPE_AGENT);
    __syncthreads();   // drains vmcnt(0): ALL threads' H stores complete at L3
    if (tid < 4)       // write-once flag to 4 replicas (plain stores, no RMW)
      __hip_atomic_store(flg_d + (size_t)s * 256 + tid * 64 + g, 1u,
                         __ATOMIC_RELAXED, __HIP_MEMORY_SCOPE_AGENT);
  }
}

// ---------------- k4: emissions GEMM (new H layout) ----------------
__global__ __launch_bounds__(256) void k4_emis(
    const unsigned short* __restrict__ Hall, const unsigned short* __restrict__ fcw_bf,
    const float* __restrict__ fcb, float* __restrict__ em) {
  __shared__ short Fs[48 * 520];
  const int tid = threadIdx.x, l = tid & 63, wv = tid >> 6;
  const int t = blockIdx.x;                      // M-tile 64 = one timestep
  floatx4 acc[3];
  acc[0] = acc[1] = acc[2] = (floatx4){0.f, 0.f, 0.f, 0.f};
  for (int half = 0; half < 2; ++half) {
    __syncthreads();
#pragma unroll
    for (int i = 0; i < 24; ++i) {
      int e4 = (tid + i * 256) * 4;
      int n = e4 >> 9, k = e4 & 511;
      *(short4v*)(Fs + n * 520 + k) =
          *(const short4v*)(fcw_bf + (size_t)n * 1024 + half * 512 + k);
    }
    __syncthreads();
    const unsigned short* Hsrc = Hall + (size_t)half * 16777216 + (size_t)permt(t) * 32768
                                 + (size_t)(wv * 16 + (l & 15)) * 512 + (l >> 4) * 8;
#pragma unroll
    for (int ks = 0; ks < 16; ++ks) {
      short8 a = *(const short8*)(Hsrc + ks * 32);
#pragma unroll
      for (int nf = 0; nf < 3; ++nf) {
        short8 bfr = *(const short8*)(Fs + (nf * 16 + (l & 15)) * 520 + ks * 32 + (l >> 4) * 8);
        acc[nf] = __builtin_amdgcn_mfma_f32_16x16x32_bf16(a, bfr, acc[nf], 0, 0, 0);
      }
    }
  }
#pragma unroll
  for (int nf = 0; nf < 3; ++nf) {
    int n = nf * 16 + (l & 15);
    float bv = fcb[n];
#pragma unroll
    for (int r = 0; r < 4; ++r) {
      int m = wv * 16 + (l >> 4) * 4 + r;        // batch
      em[((size_t)t * 64 + m) * 48 + n] = acc[nf][r] + bv;
    }
  }
}

// ---------------- k5: CRF numerator ----------------
__global__ void k5_num(const float* __restrict__ em, const int* __restrict__ tags,
                       const float* __restrict__ start, const float* __restrict__ endt,
                       const float* __restrict__ trans, float* __restrict__ num) {
  const int b = blockIdx.x, tid = threadIdx.x;
  float s = 0.f;
  for (int t = 1 + tid; t < 512; t += 256) {
    int tg = tags[b * 512 + t], tp = tags[b * 512 + t - 1];
    s += em[(size_t)(t * 64 + b) * 48 + tg] + trans[tp * 48 + tg];
  }
  if (tid == 0) {
    int t0 = tags[b * 512];
    s += start[t0] + em[(size_t)b * 48 + t0] + endt[tags[b * 512 + 511]];
  }
  __shared__ float red[256];
  red[tid] = s;
  __syncthreads();
  for (int o = 128; o > 0; o >>= 1) {
    if (tid < o) red[tid] += red[tid + o];
    __syncthreads();
  }
  if (tid == 0) num[b] = red[0];
}

// ---------------- k6: CRF forward recursion ----------------
__global__ void k6_crf(const float* __restrict__ em, const float* __restrict__ trans,
                       const float* __restrict__ start, const float* __restrict__ endt,
                       float* __restrict__ logz) {
  const int b = blockIdx.x;
  const int j = threadIdx.x;   // 64 threads, lanes 48..63 inactive
  const bool act = j < 48;
  float Ecol[48];
#pragma unroll
  for (int i = 0; i < 48; ++i) Ecol[i] = act ? __expf(trans[i * 48 + j]) : 0.f;
  __shared__ float p[48];
  float alpha = act ? (start[j] + em[(size_t)b * 48 + j]) : -1e30f;
  for (int t = 1; t < 512; ++t) {
    float e_t = act ? em[(size_t)(t * 64 + b) * 48 + j] : 0.f;
    float m = alpha;
#pragma unroll
    for (int off = 32; off > 0; off >>= 1) m = fmaxf(m, __shfl_xor(m, off));
    float pj = act ? __expf(alpha - m) : 0.f;
    if (act) p[j] = pj;
    __syncthreads();
    float ssum = 0.f;
#pragma unroll
    for (int i = 0; i < 48; ++i) ssum += p[i] * Ecol[i];
    __syncthreads();
    alpha = act ? (m + __logf(ssum) + e_t) : -1e30f;
  }
  float v = act ? (alpha + endt[j]) : -1e30f;
  float m2 = v;
#pragma unroll
  for (int off = 32; off > 0; off >>= 1) m2 = fmaxf(m2, __shfl_xor(m2, off));
  float sz = act ? __expf(v - m2) : 0.f;
#pragma unroll
  for (int off = 32; off > 0; off >>= 1) sz += __shfl_xor(sz, off);
  if (j == 0) logz[b] = m2 + __logf(sz);
}

// ---------------- k7: final scalar ----------------
__global__ void k7_final(const float* __restrict__ num, const float* __restrict__ logz,
                         float* __restrict__ out) {
  int l = threadIdx.x;
  float v = num[l] - logz[l];
#pragma unroll
  for (int off = 32; off > 0; off >>= 1) v += __shfl_xor(v, off);
  if (l == 0) out[0] = -v * (1.0f / 64.0f);
}

// ---------------------------------------------------------------------------
extern "C" void kernel_launch(void* const* d_in, const int* in_sizes, int n_in,
                              void* d_out, int out_size, void* d_ws, size_t ws_size,
                              hipStream_t stream) {
  (void)in_sizes; (void)n_in; (void)out_size;
  if (ws_size < WS_NEED) return;

  const float* embedding = (const float*)d_in[0];
  const float* w_ih_f = (const float*)d_in[1];
  const float* w_hh_f = (const float*)d_in[2];
  const float* b_ih_f = (const float*)d_in[3];
  const float* b_hh_f = (const float*)d_in[4];
  const float* w_ih_b = (const float*)d_in[5];
  const float* w_hh_b = (const float*)d_in[6];
  const float* b_ih_b = (const float*)d_in[7];
  const float* b_hh_b = (const float*)d_in[8];
  const float* fc_w = (const float*)d_in[9];
  const float* fc_b = (const float*)d_in[10];
  const float* start_trans = (const float*)d_in[11];
  const float* end_trans = (const float*)d_in[12];
  const float* trans = (const float*)d_in[13];
  const int* x = (const int*)d_in[14];
  const int* tags = (const int*)d_in[15];

  char* ws = (char*)d_ws;
  unsigned short* xq     = (unsigned short*)(ws + OFF_XQ);
  unsigned short* Hall   = (unsigned short*)(ws + OFF_H);
  unsigned short* emb_bf = (unsigned short*)(ws + OFF_EMB);
  unsigned short* wih_bf = (unsigned short*)(ws + OFF_WIH);
  unsigned short* fcw_bf = (unsigned short*)(ws + OFF_FCW);
  float* bias  = (float*)(ws + OFF_BIAS);
  float* em    = (float*)(ws + OFF_EM);
  unsigned int* flags = (unsigned int*)(ws + OFF_EM);  // alias: k3-only, k4 overwrites
  float* num   = (float*)(ws + OFF_NUM);
  float* logz  = (float*)(ws + OFF_LOGZ);

  k0_conv<<<8400, 256, 0, stream>>>(w_ih_f, w_ih_b, fc_w, b_ih_f, b_hh_f, b_ih_b, b_hh_b,
                                    wih_bf, fcw_bf, bias);
  k1_embed<<<8192, 256, 0, stream>>>(embedding, x, emb_bf);
  k2_xproj<<<dim3(256, 16, 2), 256, 0, stream>>>(emb_bf, wih_bf, bias, xq);
  k3_lstm<<<128, 256, 0, stream>>>(w_hh_f, w_hh_b, xq, Hall, flags);
  k4_emis<<<512, 256, 0, stream>>>(Hall, fcw_bf, fc_b, em);
  k5_num<<<64, 256, 0, stream>>>(em, tags, start_trans, end_trans, trans, num);
  k6_crf<<<64, 64, 0, stream>>>(em, trans, start_trans, end_trans, logz);
  k7_final<<<1, 64, 0, stream>>>(num, logz, (float*)d_out);
}

// Round 4
// 4079.274 us; speedup vs baseline: 1.9182x; 1.0544x over previous
//
#include <hip/hip_runtime.h>
#include <hip/hip_bf16.h>

// ---------------------------------------------------------------------------
// BiLSTM-CRF on MI355X, round 4.
//  Round-4 change (k3/k4): H stored in MFMA-A-fragment order
//  [d][permt(t)][mtile(4)][ks(16)][lane(64)][4 dwords] so producer stores are
//  wave-contiguous 256B (full 128B lines -> no DRAM sector RMW; r3 showed 8x
//  write amplification 532MB vs 64MB logical = the 6.7us/step pace-setter),
//  and consumer/k4 loads are perfectly coalesced 1KB/instr. Single flag copy.
//  k6: single-wave block -> barriers removed.
// ---------------------------------------------------------------------------

typedef short short8  __attribute__((ext_vector_type(8)));
typedef short short4v __attribute__((ext_vector_type(4)));
typedef float floatx4 __attribute__((ext_vector_type(4)));

#define OFF_XQ    0ULL               // [2*64][512] blocks of 2048 bf16  268,435,456 B
#define OFF_H     268435456ULL       // [2][512] frag-order blocks 64KB   67,108,864 B
#define OFF_EMB   335544320ULL       // [32768][512] bf16                 33,554,432 B
#define OFF_WIH   369098752ULL       // [2][2048][512] bf16                4,194,304 B
#define OFF_FCW   373293056ULL       // [48][1024] bf16                       98,304 B
#define OFF_BIAS  373391360ULL       // [2][2048] f32                         16,384 B
#define OFF_EM    373538816ULL       // [32768][48] f32                    6,291,456 B
                                     // (flags [2][512][64] u32 = 256 KB alias here)
#define OFF_NUM   379830272ULL       // [64] f32
#define OFF_LOGZ  379830528ULL       // [64] f32
#define WS_NEED   379830784ULL

__device__ __forceinline__ unsigned short f2bf(float f) {
  __hip_bfloat16 h = __float2bfloat16(f);
  unsigned short u; __builtin_memcpy(&u, &h, 2); return u;
}
__device__ __forceinline__ float bf2f(unsigned short u) {
  __hip_bfloat16 h; __builtin_memcpy(&h, &u, 2); return __bfloat162float(h);
}
__device__ __forceinline__ float sigm(float x) { return 1.0f / (1.0f + __expf(-x)); }
__device__ __forceinline__ float tanh_f(float x) {
  x = fmaxf(fminf(x, 15.0f), -15.0f);
  float e = __expf(2.0f * x);
  return (e - 1.0f) / (e + 1.0f);
}
// bijective time->block scramble (defeats sequential-line prefetch of unwritten blocks)
__device__ __forceinline__ int permt(int t) { return (t * 167) & 511; }

// ---------------- k0: conversions ----------------
__global__ void k0_conv(const float* __restrict__ wf, const float* __restrict__ wb,
                        const float* __restrict__ fcw,
                        const float* __restrict__ bihf, const float* __restrict__ bhhf,
                        const float* __restrict__ bihb, const float* __restrict__ bhhb,
                        unsigned short* __restrict__ wih_bf,
                        unsigned short* __restrict__ fcw_bf,
                        float* __restrict__ bias) {
  int i = blockIdx.x * 256 + threadIdx.x;
  if (i < 1048576) { wih_bf[i] = f2bf(wf[i]); return; }
  int j = i - 1048576;
  if (j < 1048576) { wih_bf[1048576 + j] = f2bf(wb[j]); return; }
  j -= 1048576;
  if (j < 49152) { fcw_bf[j] = f2bf(fcw[j]); return; }
  j -= 49152;
  if (j < 2048) { bias[j] = bihf[j] + bhhf[j]; return; }
  j -= 2048;
  if (j < 2048) { bias[2048 + j] = bihb[j] + bhhb[j]; return; }
}

// ---------------- k1: embedding gather -> bf16 ----------------
__global__ void k1_embed(const float* __restrict__ tab, const int* __restrict__ x,
                         unsigned short* __restrict__ emb_bf) {
  int tid = threadIdx.x;
#pragma unroll
  for (int r = 0; r < 4; ++r) {
    int m = blockIdx.x * 4 + r;          // m = t*64 + b
    int b = m & 63, t = m >> 6;
    int tok = x[b * 512 + t];
    const float2* src = (const float2*)(tab + (size_t)tok * 512);
    float2 v = src[tid];
    unsigned int pk = (unsigned int)f2bf(v.x) | ((unsigned int)f2bf(v.y) << 16);
    ((unsigned int*)(emb_bf + (size_t)m * 512))[tid] = pk;
  }
}

// ---------------- k2: input-projection GEMM -> xq layout ----------------
// xq block index (d*64+g)*512 + t, 2048 bf16 per block, inner: gate*512 + b*8 + ce
__global__ __launch_bounds__(256) void k2_xproj(
    const unsigned short* __restrict__ emb_bf, const unsigned short* __restrict__ wih_bf,
    const float* __restrict__ bias, unsigned short* __restrict__ xq) {
  const int mt = blockIdx.x * 128;
  const int nt = blockIdx.y * 128;
  const int d  = blockIdx.z;
  const unsigned short* W = wih_bf + (size_t)d * 2048 * 512;
  __shared__ short Bs[32768];                     // 64 KB (also epilogue scratch)
  const int tid = threadIdx.x, l = tid & 63, wv = tid >> 6;
  const int mh = wv & 1, nh = wv >> 1;
  floatx4 acc[4][4];
#pragma unroll
  for (int a = 0; a < 4; ++a)
#pragma unroll
    for (int b = 0; b < 4; ++b) acc[a][b] = (floatx4){0.f, 0.f, 0.f, 0.f};
  const unsigned short* Abase = emb_bf + (size_t)(mt + mh * 64) * 512;

  for (int kc = 0; kc < 2; ++kc) {
    __syncthreads();
#pragma unroll
    for (int i = 0; i < 16; ++i) {                // stage 64 B-fragments
      int f = i * 4 + wv;
      int nb2 = f & 7, ks = f >> 3;
      int n = nt + nb2 * 16 + (l & 15);
      int k = kc * 256 + ks * 32 + (l >> 4) * 8;
      short8 v = *(const short8*)(W + (size_t)n * 512 + k);
      *(short8*)(Bs + (f * 64 + l) * 8) = v;
    }
    __syncthreads();
#pragma unroll
    for (int ks = 0; ks < 8; ++ks) {
      int k0 = kc * 256 + ks * 32 + (l >> 4) * 8;
      short8 a[4];
#pragma unroll
      for (int mf = 0; mf < 4; ++mf)
        a[mf] = *(const short8*)(Abase + (size_t)(mf * 16 + (l & 15)) * 512 + k0);
#pragma unroll
      for (int nf = 0; nf < 4; ++nf) {
        short8 bfr = *(const short8*)(Bs + ((ks * 8 + nh * 4 + nf) * 64 + l) * 8);
#pragma unroll
        for (int mf = 0; mf < 4; ++mf)
          acc[mf][nf] = __builtin_amdgcn_mfma_f32_16x16x32_bf16(a[mf], bfr, acc[mf][nf], 0, 0, 0);
      }
    }
  }
  // ---- epilogue: LDS transpose into xq block layout ----
  __syncthreads();
#pragma unroll
  for (int nf = 0; nf < 4; ++nf) {
    int nl = nh * 64 + nf * 16 + (l & 15);
    float bs = bias[d * 2048 + nt + nl];
#pragma unroll
    for (int mf = 0; mf < 4; ++mf)
#pragma unroll
      for (int r = 0; r < 4; ++r) {
        int ml = mh * 64 + mf * 16 + (l >> 4) * 4 + r;
        Bs[ml * 136 + nl] = (short)f2bf(acc[mf][nf][r] + bs);  // stride 136: 16B-aligned rows
      }
  }
  __syncthreads();
  const int chunk = tid >> 3, sub = tid & 7;      // 32 chunks x 8 threads
  const int g_l = chunk & 15, t_l = chunk >> 4;
  const int gate = nt >> 9, g0 = (nt & 511) >> 3;
  size_t base = (((size_t)(d * 64 + g0 + g_l) * 512) + (size_t)(blockIdx.x * 2 + t_l)) * 2048
                + (size_t)gate * 512 + (size_t)sub * 64;
#pragma unroll
  for (int i = 0; i < 8; ++i) {                   // b = sub*8+i, pos = b*8+ce
    short8 v = *(const short8*)(Bs + (t_l * 64 + sub * 8 + i) * 136 + g_l * 8);
    *(short8*)(xq + base + i * 8) = v;
  }
}

// ---------------- k3: persistent BiLSTM, frag-order H, coalesced stores ----------------
__global__ __launch_bounds__(256, 1) void k3_lstm(
    const float* __restrict__ whh_f, const float* __restrict__ whh_b,
    const unsigned short* __restrict__ xq, unsigned short* __restrict__ Hall,
    unsigned int* __restrict__ flags) {
  const int wgid = blockIdx.x;
  const int d = wgid >> 6, g = wgid & 63;
  const int tid = threadIdx.x, l = tid & 63, wv = tid >> 6;
  const float* whh = d ? whh_b : whh_f;

  // W_hh tile (cells [g*8,g*8+8) x 4 gates) as 32 B-fragments in VGPRs.
  short8 Bf[32];
#pragma unroll
  for (int ks = 0; ks < 16; ++ks) {
#pragma unroll
    for (int nf = 0; nf < 2; ++nf) {
      int nl = nf * 16 + (l & 15);
      int gate = nl >> 3, cell = nl & 7;
      int row = gate * 512 + g * 8 + cell;
      int k0 = ks * 32 + (l >> 4) * 8;
      const float* src = whh + (size_t)row * 512 + k0;
      short8 v;
#pragma unroll
      for (int j = 0; j < 8; ++j) v[j] = (short)f2bf(src[j]);
      Bf[ks * 2 + nf] = v;
    }
  }

  __shared__ float gsh2[32][66];                  // [gate*8+cell][batch], transposed
  // elementwise mapping chosen so the H store is wave-contiguous in frag order:
  //   eb = (tid>>6)*16 + ((tid&63)>>2)   (batch), pr = tid&3 (cell pair)
  const int i6 = tid & 63, q = tid >> 6;
  const int eb = q * 16 + (i6 >> 2);
  const int pr = tid & 3;
  float cst[2] = {0.f, 0.f};

  const unsigned short* Hd = Hall + (size_t)d * 16777216;
  unsigned int* Hw = (unsigned int*)Hall + (size_t)d * 8388608;
  const unsigned short* xqd = xq + ((size_t)(d * 64 + g) * 512) * 2048;
  unsigned int* flg_d = flags + (size_t)d * 512 * 64;   // [512][64]

  // per-thread store dword index within a (d,t) 16384-dword frag block:
  const int st_idx = (q * 16 + (g >> 2)) * 256 + 64 * (g & 3) + i6;

  for (int s = 0; s < 512; ++s) {
    const int t = d ? (511 - s) : s;

    // prefetch xq (single-use, issued before the wait) — coalesced: dword [gate*256+tid]
    const unsigned int* xb = (const unsigned int*)(xqd + (size_t)t * 2048);
    unsigned int xg[4];
#pragma unroll
    for (int gate = 0; gate < 4; ++gate) xg[gate] = xb[gate * 256 + tid];

    floatx4 acc0 = (floatx4){0.f, 0.f, 0.f, 0.f};
    floatx4 acc1 = (floatx4){0.f, 0.f, 0.f, 0.f};
    if (s > 0) {
      const unsigned int* fp = flg_d + (size_t)(s - 1) * 64 + l;
      for (;;) {
        unsigned int v = __hip_atomic_load(fp, __ATOMIC_RELAXED, __HIP_MEMORY_SCOPE_AGENT);
        if (__all(v == 1u)) break;
        __builtin_amdgcn_s_sleep(1);
      }
      asm volatile("" ::: "memory");              // pin H loads after poll (compiler only)
      const int tp = d ? (t + 1) : (t - 1);
      // frag-order load: 1KB contiguous per instruction
      const unsigned short* Hrow = Hd + (size_t)permt(tp) * 32768 + (size_t)wv * 8192 + l * 8;
      short8 af[16];
#pragma unroll
      for (int ks = 0; ks < 16; ++ks) af[ks] = *(const short8*)(Hrow + ks * 512);
#pragma unroll
      for (int ks = 0; ks < 16; ++ks) {
        acc0 = __builtin_amdgcn_mfma_f32_16x16x32_bf16(af[ks], Bf[ks * 2 + 0], acc0, 0, 0, 0);
        acc1 = __builtin_amdgcn_mfma_f32_16x16x32_bf16(af[ks], Bf[ks * 2 + 1], acc1, 0, 0, 0);
      }
    }
    // stage gates transposed: row = gate*8+cell (0..31), col = batch
#pragma unroll
    for (int r = 0; r < 4; ++r) {
      int m = wv * 16 + (l >> 4) * 4 + r;
      gsh2[l & 15][m] = acc0[r];
      gsh2[16 + (l & 15)][m] = acc1[r];
    }
    __syncthreads();
    // elementwise: thread owns cells pr*2, pr*2+1 of batch eb
    float h2[2];
#pragma unroll
    for (int ci = 0; ci < 2; ++ci) {
      int cl = pr * 2 + ci;
      float gi = gsh2[0 + cl][eb]  + bf2f((unsigned short)(xg[0] >> (ci * 16)));
      float gf = gsh2[8 + cl][eb]  + bf2f((unsigned short)(xg[1] >> (ci * 16)));
      float gg = gsh2[16 + cl][eb] + bf2f((unsigned short)(xg[2] >> (ci * 16)));
      float go = gsh2[24 + cl][eb] + bf2f((unsigned short)(xg[3] >> (ci * 16)));
      float c = sigm(gf) * cst[ci] + sigm(gi) * tanh_f(gg);
      cst[ci] = c;
      h2[ci] = sigm(go) * tanh_f(c);
    }
    unsigned int hp = (unsigned int)f2bf(h2[0]) | ((unsigned int)f2bf(h2[1]) << 16);
    // write-through agent atomic store, wave-contiguous 256B -> full-line writes
    __hip_atomic_store(&Hw[(size_t)permt(t) * 16384 + st_idx], hp,
                       __ATOMIC_RELAXED, __HIP_MEMORY_SCOPE_AGENT);
    __syncthreads();   // drains vmcnt(0): ALL threads' H stores complete
    if (tid == 0)      // write-once flag (single copy; r3 proved contention irrelevant)
      __hip_atomic_store(flg_d + (size_t)s * 64 + g, 1u,
                         __ATOMIC_RELAXED, __HIP_MEMORY_SCOPE_AGENT);
  }
}

// ---------------- k4: emissions GEMM (frag-order H) ----------------
__global__ __launch_bounds__(256) void k4_emis(
    const unsigned short* __restrict__ Hall, const unsigned short* __restrict__ fcw_bf,
    const float* __restrict__ fcb, float* __restrict__ em) {
  __shared__ short Fs[48 * 520];
  const int tid = threadIdx.x, l = tid & 63, wv = tid >> 6;
  const int t = blockIdx.x;                      // M-tile 64 = one timestep
  floatx4 acc[3];
  acc[0] = acc[1] = acc[2] = (floatx4){0.f, 0.f, 0.f, 0.f};
  for (int half = 0; half < 2; ++half) {
    __syncthreads();
#pragma unroll
    for (int i = 0; i < 24; ++i) {
      int e4 = (tid + i * 256) * 4;
      int n = e4 >> 9, k = e4 & 511;
      *(short4v*)(Fs + n * 520 + k) =
          *(const short4v*)(fcw_bf + (size_t)n * 1024 + half * 512 + k);
    }
    __syncthreads();
    const unsigned short* Hsrc = Hall + (size_t)half * 16777216 + (size_t)permt(t) * 32768
                                 + (size_t)wv * 8192 + l * 8;
#pragma unroll
    for (int ks = 0; ks < 16; ++ks) {
      short8 a = *(const short8*)(Hsrc + ks * 512);
#pragma unroll
      for (int nf = 0; nf < 3; ++nf) {
        short8 bfr = *(const short8*)(Fs + (nf * 16 + (l & 15)) * 520 + ks * 32 + (l >> 4) * 8);
        acc[nf] = __builtin_amdgcn_mfma_f32_16x16x32_bf16(a, bfr, acc[nf], 0, 0, 0);
      }
    }
  }
#pragma unroll
  for (int nf = 0; nf < 3; ++nf) {
    int n = nf * 16 + (l & 15);
    float bv = fcb[n];
#pragma unroll
    for (int r = 0; r < 4; ++r) {
      int m = wv * 16 + (l >> 4) * 4 + r;        // batch
      em[((size_t)t * 64 + m) * 48 + n] = acc[nf][r] + bv;
    }
  }
}

// ---------------- k5: CRF numerator ----------------
__global__ void k5_num(const float* __restrict__ em, const int* __restrict__ tags,
                       const float* __restrict__ start, const float* __restrict__ endt,
                       const float* __restrict__ trans, float* __restrict__ num) {
  const int b = blockIdx.x, tid = threadIdx.x;
  float s = 0.f;
  for (int t = 1 + tid; t < 512; t += 256) {
    int tg = tags[b * 512 + t], tp = tags[b * 512 + t - 1];
    s += em[(size_t)(t * 64 + b) * 48 + tg] + trans[tp * 48 + tg];
  }
  if (tid == 0) {
    int t0 = tags[b * 512];
    s += start[t0] + em[(size_t)b * 48 + t0] + endt[tags[b * 512 + 511]];
  }
  __shared__ float red[256];
  red[tid] = s;
  __syncthreads();
  for (int o = 128; o > 0; o >>= 1) {
    if (tid < o) red[tid] += red[tid + o];
    __syncthreads();
  }
  if (tid == 0) num[b] = red[0];
}

// ---------------- k6: CRF forward recursion (single wave, no barriers) ----------------
__global__ void k6_crf(const float* __restrict__ em, const float* __restrict__ trans,
                       const float* __restrict__ start, const float* __restrict__ endt,
                       float* __restrict__ logz) {
  const int b = blockIdx.x;
  const int j = threadIdx.x;   // 64 threads = ONE wave; lanes 48..63 inactive
  const bool act = j < 48;
  float Ecol[48];
#pragma unroll
  for (int i = 0; i < 48; ++i) Ecol[i] = act ? __expf(trans[i * 48 + j]) : 0.f;
  __shared__ float p[48];
  float alpha = act ? (start[j] + em[(size_t)b * 48 + j]) : -1e30f;
  for (int t = 1; t < 512; ++t) {
    float e_t = act ? em[(size_t)(t * 64 + b) * 48 + j] : 0.f;
    float m = alpha;
#pragma unroll
    for (int off = 32; off > 0; off >>= 1) m = fmaxf(m, __shfl_xor(m, off));
    if (act) p[j] = __expf(alpha - m);
    float ssum = 0.f;                       // single wave: LDS ops in-order, no barrier
#pragma unroll
    for (int i = 0; i < 48; ++i) ssum += p[i] * Ecol[i];
    alpha = act ? (m + __logf(ssum) + e_t) : -1e30f;
  }
  float v = act ? (alpha + endt[j]) : -1e30f;
  float m2 = v;
#pragma unroll
  for (int off = 32; off > 0; off >>= 1) m2 = fmaxf(m2, __shfl_xor(m2, off));
  float sz = act ? __expf(v - m2) : 0.f;
#pragma unroll
  for (int off = 32; off > 0; off >>= 1) sz += __shfl_xor(sz, off);
  if (j == 0) logz[b] = m2 + __logf(sz);
}

// ---------------- k7: final scalar ----------------
__global__ void k7_final(const float* __restrict__ num, const float* __restrict__ logz,
                         float* __restrict__ out) {
  int l = threadIdx.x;
  float v = num[l] - logz[l];
#pragma unroll
  for (int off = 32; off > 0; off >>= 1) v += __shfl_xor(v, off);
  if (l == 0) out[0] = -v * (1.0f / 64.0f);
}

// ---------------------------------------------------------------------------
extern "C" void kernel_launch(void* const* d_in, const int* in_sizes, int n_in,
                              void* d_out, int out_size, void* d_ws, size_t ws_size,
                              hipStream_t stream) {
  (void)in_sizes; (void)n_in; (void)out_size;
  if (ws_size < WS_NEED) return;

  const float* embedding = (const float*)d_in[0];
  const float* w_ih_f = (const float*)d_in[1];
  const float* w_hh_f = (const float*)d_in[2];
  const float* b_ih_f = (const float*)d_in[3];
  const float* b_hh_f = (const float*)d_in[4];
  const float* w_ih_b = (const float*)d_in[5];
  const float* w_hh_b = (const float*)d_in[6];
  const float* b_ih_b = (const float*)d_in[7];
  const float* b_hh_b = (const float*)d_in[8];
  const float* fc_w = (const float*)d_in[9];
  const float* fc_b = (const float*)d_in[10];
  const float* start_trans = (const float*)d_in[11];
  const float* end_trans = (const float*)d_in[12];
  const float* trans = (const float*)d_in[13];
  const int* x = (const int*)d_in[14];
  const int* tags = (const int*)d_in[15];

  char* ws = (char*)d_ws;
  unsigned short* xq     = (unsigned short*)(ws + OFF_XQ);
  unsigned short* Hall   = (unsigned short*)(ws + OFF_H);
  unsigned short* emb_bf = (unsigned short*)(ws + OFF_EMB);
  unsigned short* wih_bf = (unsigned short*)(ws + OFF_WIH);
  unsigned short* fcw_bf = (unsigned short*)(ws + OFF_FCW);
  float* bias  = (float*)(ws + OFF_BIAS);
  float* em    = (float*)(ws + OFF_EM);
  unsigned int* flags = (unsigned int*)(ws + OFF_EM);  // alias: k3-only, k4 overwrites
  float* num   = (float*)(ws + OFF_NUM);
  float* logz  = (float*)(ws + OFF_LOGZ);

  k0_conv<<<8400, 256, 0, stream>>>(w_ih_f, w_ih_b, fc_w, b_ih_f, b_hh_f, b_ih_b, b_hh_b,
                                    wih_bf, fcw_bf, bias);
  k1_embed<<<8192, 256, 0, stream>>>(embedding, x, emb_bf);
  k2_xproj<<<dim3(256, 16, 2), 256, 0, stream>>>(emb_bf, wih_bf, bias, xq);
  k3_lstm<<<128, 256, 0, stream>>>(w_hh_f, w_hh_b, xq, Hall, flags);
  k4_emis<<<512, 256, 0, stream>>>(Hall, fcw_bf, fc_b, em);
  k5_num<<<64, 256, 0, stream>>>(em, tags, start_trans, end_trans, trans, num);
  k6_crf<<<64, 64, 0, stream>>>(em, trans, start_trans, end_trans, logz);
  k7_final<<<1, 64, 0, stream>>>(num, logz, (float*)d_out);
}